// Round 1
// 722.471 us; speedup vs baseline: 1.2397x; 1.2397x over previous
//
#include <hip/hip_runtime.h>
#include <cstdint>

// Problem: y = x @ dequant(peso, escala)^T
//   x:      [M=4096, K=4096]  f32  (B=2, S=2048 flattened)
//   peso:   [N=12288, K=4096] f32
//   escala: [N/128, K/128]    f32
//   y:      [M, N]            f32
// Strategy: prepass-convert both operands to bf16 in d_ws (dequant fused into
// the weight conversion), then run the 256x256 8-phase MFMA GEMM (T1+T2+T3+T4+T5):
//  - 8 waves, BK=64 split into two 32-wide half-steps, 4-slot LDS ring/operand
//  - raw s_barrier + counted vmcnt(4) once per K-tile (loads stay in flight)
//  - XOR-swizzled LDS (involution on byte bits 4-5 from row bits 1-2),
//    applied to the global SOURCE of global_load_lds and to ds_read addrs
//  - setprio(1) around each 16-MFMA cluster; bijective XCD blockIdx swizzle

typedef __bf16 bf16x8 __attribute__((ext_vector_type(8)));
typedef float  f32x4  __attribute__((ext_vector_type(4)));

__device__ __forceinline__ ushort f32_to_bf16_rne(float f) {
    union { float f; uint32_t u; } v; v.f = f;
    uint32_t u = v.u;
    return (ushort)((u + 0x7FFFu + ((u >> 16) & 1u)) >> 16);
}

__device__ __forceinline__ void async16(const ushort* g, ushort* l) {
    // global -> LDS direct copy, 16 B/lane; LDS dest = wave-uniform base + lane*16
    __builtin_amdgcn_global_load_lds(
        (const __attribute__((address_space(1))) void*)g,
        (__attribute__((address_space(3))) void*)l,
        16, 0, 0);
}

// ---------------- prepass 1: x f32 -> bf16 ----------------
__global__ void convert_x_kernel(const float* __restrict__ x,
                                 ushort* __restrict__ xb, int n4) {
    int t = blockIdx.x * blockDim.x + threadIdx.x;
    if (t >= n4) return;
    float4 v = ((const float4*)x)[t];
    ushort4 o;
    o.x = f32_to_bf16_rne(v.x);
    o.y = f32_to_bf16_rne(v.y);
    o.z = f32_to_bf16_rne(v.z);
    o.w = f32_to_bf16_rne(v.w);
    ((ushort4*)xb)[t] = o;
}

// ---------------- prepass 2: W = peso * escala, f32 -> bf16 ----------------
__global__ void dequant_w_kernel(const float* __restrict__ w,
                                 const float* __restrict__ s,
                                 ushort* __restrict__ wb, int n4) {
    int t = blockIdx.x * blockDim.x + threadIdx.x;
    if (t >= n4) return;
    int e = t << 2;                 // element index
    int o = e >> 12;                // / 4096
    int i = e & 4095;
    float sc = s[(o >> 7) * 32 + (i >> 7)];
    float4 v = ((const float4*)w)[t];
    ushort4 u;
    u.x = f32_to_bf16_rne(v.x * sc);
    u.y = f32_to_bf16_rne(v.y * sc);
    u.z = f32_to_bf16_rne(v.z * sc);
    u.w = f32_to_bf16_rne(v.w * sc);
    ((ushort4*)wb)[t] = u;
}

// ---------------- main GEMM: C[M,N] = A[M,K] @ B[N,K]^T, 256^2 8-phase ----------------
// LDS map (dynamic, 128 KiB):
//   A slots: 4 x [256 rows][32 k] bf16 = 4 x 16 KiB at byte 0
//   B slots: 4 x [256 rows][32 k] bf16 = 4 x 16 KiB at byte 65536
// slot(khalf) = khalf & 3, khalf = 2*tile + ks.
__global__ __launch_bounds__(512) void gemm256_8ph(
    const ushort* __restrict__ A,   // [M][K] bf16 bits
    const ushort* __restrict__ B,   // [N][K] bf16 bits
    float* __restrict__ C,          // [M][N] f32
    int M, int N, int K)
{
    extern __shared__ char smc[];

    const int tid  = threadIdx.x;
    const int wave = tid >> 6;         // 0..7
    const int lane = tid & 63;
    const int quad = lane >> 4;        // 0..3
    const int l15  = lane & 15;

    // bijective XCD swizzle (grid 768 = 8*96)
    int wg = blockIdx.x;
    if ((gridDim.x & 7) == 0) {
        const int cpx = gridDim.x >> 3;
        wg = (wg & 7) * cpx + (wg >> 3);
    }
    const int nbx = N >> 8;
    const int bx = wg % nbx, by = wg / nbx;
    const int m0 = by << 8, n0 = bx << 8;

    const int wr = wave >> 2;          // 0..1 : wave's 128-row M half
    const int wc = wave & 3;           // 0..3 : wave's 64-col N quarter

    // ds_read fragment byte offsets within a slot (swizzle depends only on l15)
    const int swz  = ((l15 >> 1) & 3) << 4;
    const int aoff = (wr * 128 + l15) * 64 + ((quad * 16) ^ swz);
    const int boff = (wc * 64  + l15) * 64 + ((quad * 16) ^ swz);

    // staging: lane's linear LDS dest byte = base + lane*16 -> row = lane>>2,
    // 16B col slot = lane&3; pre-swizzle the GLOBAL source (involution).
    const int csrc = (((lane & 3) * 16) ^ (((lane >> 3) & 3) << 4)) >> 1; // elem
    const int srow = wave * 16 + (lane >> 2);
    const ushort* gA0 = A + (size_t)(m0 +       srow) * K + csrc;
    const ushort* gA1 = A + (size_t)(m0 + 128 + srow) * K + csrc;
    const ushort* gB0 = B + (size_t)(n0 +       srow) * K + csrc;
    const ushort* gB1 = B + (size_t)(n0 + 128 + srow) * K + csrc;

    const int ldsw = wave * 1024;      // wave-uniform byte offset within half-slot

    #define STG_A(S, KC) do { \
        async16(gA0 + (KC), (ushort*)(smc + (S)*16384 + ldsw)); \
        async16(gA1 + (KC), (ushort*)(smc + (S)*16384 + 8192 + ldsw)); } while (0)
    #define STG_B(S, KC) do { \
        async16(gB0 + (KC), (ushort*)(smc + 65536 + (S)*16384 + ldsw)); \
        async16(gB1 + (KC), (ushort*)(smc + 65536 + (S)*16384 + 8192 + ldsw)); } while (0)

    f32x4 acc[8][4];
    #pragma unroll
    for (int i = 0; i < 8; ++i)
        #pragma unroll
        for (int j = 0; j < 4; ++j)
            acc[i][j] = f32x4{0.f, 0.f, 0.f, 0.f};

    const int NTl = K >> 6;            // 64 K-tiles of BK=64 (even)

    // ---- prologue: stage tile0 (both halves) + tile1 (ks0); keep order for vmcnt
    STG_A(0, 0);   STG_B(0, 0);   __builtin_amdgcn_sched_barrier(0);
    STG_A(1, 32);  STG_B(1, 32);  __builtin_amdgcn_sched_barrier(0);
    STG_A(2, 64);  STG_B(2, 64);  __builtin_amdgcn_sched_barrier(0);
    asm volatile("s_waitcnt vmcnt(4)" ::: "memory");  // tile0 complete, tile1-ks0 in flight
    __builtin_amdgcn_sched_barrier(0);
    __builtin_amdgcn_s_barrier();
    __builtin_amdgcn_sched_barrier(0);

    bf16x8 af[4], bfr[4];

    #define LD_A(S, MH) \
        _Pragma("unroll") \
        for (int i = 0; i < 4; ++i) \
            af[i] = *(const bf16x8*)(smc + (S)*16384 + aoff + (MH)*4096 + i*1024);
    #define LD_B(S) \
        _Pragma("unroll") \
        for (int j = 0; j < 4; ++j) \
            bfr[j] = *(const bf16x8*)(smc + 65536 + (S)*16384 + boff + j*1024);

    #define PB() do { \
        __builtin_amdgcn_sched_barrier(0); \
        asm volatile("" ::: "memory"); \
        __builtin_amdgcn_s_barrier(); \
        __builtin_amdgcn_sched_barrier(0); } while (0)

    #define MFMA16(MH) do { \
        __builtin_amdgcn_s_setprio(1); \
        _Pragma("unroll") \
        for (int i = 0; i < 4; ++i) { \
            _Pragma("unroll") \
            for (int j = 0; j < 4; ++j) \
                acc[(MH)*4 + i][j] = __builtin_amdgcn_mfma_f32_16x16x32_bf16( \
                    af[i], bfr[j], acc[(MH)*4 + i][j], 0, 0, 0); \
        } \
        __builtin_amdgcn_s_setprio(0); } while (0)

    // One K-tile = 4 phases. Issue schedule (1 half-tile/phase, wraps mod NTl):
    //   P1: A(t+1,ks1)->S3   P2: B(t+1,ks1)->S3   P3: A(t+2,ks0)->S0   P4: B(t+2,ks0)->S0
    // Slot lifetimes: A-S0 last read P2, restaged P3; B-S0 last read P1, restaged P4;
    // ks1 slots last read P3/P4, restaged next tile's P1/P2 — all barrier-separated.
    // vmcnt(4) at P4 end leaves exactly {A,B}(t+2,ks0) in flight => tile t+1 staged.
    #define KTILE(T, S0, S1, S3) do { \
        int t1 = (T) + 1; if (t1 == NTl) t1 = 0; \
        int t2 = (T) + 2; if (t2 >= NTl) t2 -= NTl; \
        const int kA1 = t1 * 64 + 32, kA2 = t2 * 64; \
        /* P1: mh0, ks0 */ \
        LD_A(S0, 0); LD_B(S0); \
        STG_A(S3, kA1); \
        PB(); MFMA16(0); PB(); \
        /* P2: mh1, ks0 */ \
        LD_A(S0, 1); \
        STG_B(S3, kA1); \
        PB(); MFMA16(1); PB(); \
        /* P3: mh0, ks1 */ \
        LD_A(S1, 0); LD_B(S1); \
        STG_A(S0, kA2); \
        PB(); MFMA16(0); PB(); \
        /* P4: mh1, ks1 */ \
        LD_A(S1, 1); \
        STG_B(S0, kA2); \
        PB(); \
        MFMA16(1); \
        asm volatile("s_waitcnt vmcnt(4)" ::: "memory"); \
        PB(); } while (0)

    #pragma unroll 1
    for (int t = 0; t < NTl; t += 2) {
        KTILE(t,     0, 1, 3);
        KTILE(t + 1, 2, 3, 1);
    }

    // ---- epilogue: D layout col=lane&15, row=quad*4+reg (m89-verified)
    #pragma unroll
    for (int i = 0; i < 8; ++i) {
        const int row0 = m0 + wr * 128 + i * 16 + quad * 4;
        #pragma unroll
        for (int j = 0; j < 4; ++j) {
            const int col = n0 + wc * 64 + j * 16 + l15;
            #pragma unroll
            for (int r = 0; r < 4; ++r)
                C[(size_t)(row0 + r) * N + col] = acc[i][j][r];
        }
    }

    #undef KTILE
    #undef MFMA16
    #undef PB
    #undef LD_B
    #undef LD_A
    #undef STG_B
    #undef STG_A
}

// ---------------- emergency fallback (ws too small): correct but slow ----------------
__global__ void fallback_kernel(const float* __restrict__ x,
                                const float* __restrict__ w,
                                const float* __restrict__ s,
                                float* __restrict__ y,
                                int M, int N, int K) {
    long long idx = (long long)blockIdx.x * blockDim.x + threadIdx.x;
    if (idx >= (long long)M * N) return;
    int m = (int)(idx / N), n = (int)(idx % N);
    const float* xr = x + (size_t)m * K;
    const float* wr = w + (size_t)n * K;
    const float* sr = s + (size_t)(n >> 7) * (K >> 7);
    float acc = 0.f;
    for (int k = 0; k < K; ++k)
        acc += xr[k] * wr[k] * sr[k >> 7];
    y[idx] = acc;
}

extern "C" void kernel_launch(void* const* d_in, const int* in_sizes, int n_in,
                              void* d_out, int out_size, void* d_ws, size_t ws_size,
                              hipStream_t stream) {
    const float* x      = (const float*)d_in[0];
    const float* peso   = (const float*)d_in[1];
    const float* escala = (const float*)d_in[2];
    float* y = (float*)d_out;

    const int K = 4096;
    const int N = 12288;
    const int M = in_sizes[0] / K;   // 4096

    const size_t xb_elems = (size_t)M * K;
    const size_t wb_elems = (size_t)N * K;
    const size_t need = (xb_elems + wb_elems) * sizeof(ushort);  // 128 MB

    if (ws_size >= need && (M & 255) == 0) {
        ushort* xb = (ushort*)d_ws;
        ushort* wb = xb + xb_elems;

        const int nx4 = (int)(xb_elems / 4);
        convert_x_kernel<<<(nx4 + 255) / 256, 256, 0, stream>>>(x, xb, nx4);

        const int nw4 = (int)(wb_elems / 4);
        dequant_w_kernel<<<(nw4 + 255) / 256, 256, 0, stream>>>(peso, escala, wb, nw4);

        static bool attr_done = false;
        if (!attr_done) {
            (void)hipFuncSetAttribute(reinterpret_cast<const void*>(&gemm256_8ph),
                                      hipFuncAttributeMaxDynamicSharedMemorySize,
                                      131072);
            attr_done = true;
        }

        const int nblk = (M >> 8) * (N >> 8);   // 16*48 = 768
        gemm256_8ph<<<dim3(nblk), dim3(512), 131072, stream>>>(xb, wb, y, M, N, K);
    } else {
        long long total = (long long)M * N;
        int blocks = (int)((total + 255) / 256);
        fallback_kernel<<<blocks, 256, 0, stream>>>(x, peso, escala, y, M, N, K);
    }
}